// Round 4
// baseline (928.461 us; speedup 1.0000x reference)
//
#include <hip/hip_runtime.h>
#include <hip/hip_bf16.h>

#define IN_DIM 128
#define OUT_DIM 64
#define BN_EPS 1e-5f
#define BSH 7                  // 128 nodes per bucket
#define BROWS 128
#define ASTR 68                // padded LDS row stride (floats): spreads banks
#define MAXBUCK 800            // LDS array bound (>= nbuck = 782)

// ---------------- kernels ----------------

// bucket histogram (block-aggregated) + per-node degree, fused
__global__ __launch_bounds__(256) void k_bhist(const int4* __restrict__ dst4, int E4,
                                               int nbuck, int* __restrict__ deg,
                                               int* __restrict__ gbcnt) {
    __shared__ int hcnt[MAXBUCK];
    for (int i = threadIdx.x; i < nbuck; i += 256) hcnt[i] = 0;
    __syncthreads();
    int base = blockIdx.x * 1024 + threadIdx.x;
    #pragma unroll
    for (int j = 0; j < 4; ++j) {
        int i4 = base + j * 256;
        if (i4 < E4) {
            int4 v = dst4[i4];
            atomicAdd(&deg[v.x], 1); atomicAdd(&hcnt[v.x >> BSH], 1);
            atomicAdd(&deg[v.y], 1); atomicAdd(&hcnt[v.y >> BSH], 1);
            atomicAdd(&deg[v.z], 1); atomicAdd(&hcnt[v.z >> BSH], 1);
            atomicAdd(&deg[v.w], 1); atomicAdd(&hcnt[v.w >> BSH], 1);
        }
    }
    __syncthreads();
    for (int i = threadIdx.x; i < nbuck; i += 256)
        if (hcnt[i]) atomicAdd(&gbcnt[i], hcnt[i]);
}

// exclusive scan of bucket counts (nbuck <= 1024), one block
__global__ __launch_bounds__(1024) void k_bscan(const int* __restrict__ gbcnt, int nbuck,
                                                int E, int* __restrict__ gbase,
                                                int* __restrict__ gcursor) {
    __shared__ int sh[1024];
    int t = threadIdx.x;
    int v = (t < nbuck) ? gbcnt[t] : 0;
    sh[t] = v;
    __syncthreads();
    for (int d = 1; d < 1024; d <<= 1) {
        int tv = (t >= d) ? sh[t - d] : 0;
        __syncthreads();
        sh[t] += tv;
        __syncthreads();
    }
    if (t < nbuck) {
        int b = sh[t] - v;
        gbase[t] = b;
        gcursor[t] = b;
    }
    if (t == 1023) gbase[nbuck] = E;
}

__global__ __launch_bounds__(256) void k_dinv(const int* __restrict__ deg,
                                              float* __restrict__ dinv, int N) {
    int i = blockIdx.x * 256 + threadIdx.x;
    if (i < N) dinv[i] = rsqrtf((float)(deg[i] + 1));
}

// m = (x @ W) * dinv[n].  Block: 16 nodes, 4 waves; each wave computes 4 nodes.
__global__ __launch_bounds__(256) void k_gemm(const float* __restrict__ x,
                                              const float* __restrict__ W,
                                              const float* __restrict__ dinv,
                                              float* __restrict__ m, int N) {
    __shared__ float Wl[IN_DIM * OUT_DIM];  // 32 KB
    __shared__ float xl[16 * IN_DIM];       // 8 KB

    for (int i = threadIdx.x; i < (IN_DIM * OUT_DIM) / 4; i += 256)
        ((float4*)Wl)[i] = ((const float4*)W)[i];

    int node0 = blockIdx.x * 16;
    for (int i = threadIdx.x; i < 16 * IN_DIM / 4; i += 256) {
        int n = node0 + (i >> 5);
        if (n < N)
            ((float4*)xl)[i] = ((const float4*)x)[(size_t)node0 * (IN_DIM / 4) + i];
    }
    __syncthreads();

    int wave = threadIdx.x >> 6;
    int lane = threadIdx.x & 63;
    int nb = node0 + wave * 4;

    float acc[4] = {0.f, 0.f, 0.f, 0.f};
    for (int k0 = 0; k0 < IN_DIM; k0 += 4) {
        float4 xv0 = ((float4*)xl)[((wave * 4 + 0) * IN_DIM + k0) >> 2];
        float4 xv1 = ((float4*)xl)[((wave * 4 + 1) * IN_DIM + k0) >> 2];
        float4 xv2 = ((float4*)xl)[((wave * 4 + 2) * IN_DIM + k0) >> 2];
        float4 xv3 = ((float4*)xl)[((wave * 4 + 3) * IN_DIM + k0) >> 2];
        #pragma unroll
        for (int kk = 0; kk < 4; ++kk) {
            float w = Wl[(k0 + kk) * OUT_DIM + lane];
            acc[0] += ((float*)&xv0)[kk] * w;
            acc[1] += ((float*)&xv1)[kk] * w;
            acc[2] += ((float*)&xv2)[kk] * w;
            acc[3] += ((float*)&xv3)[kk] * w;
        }
    }
    #pragma unroll
    for (int j = 0; j < 4; ++j) {
        int n = nb + j;
        if (n < N) m[(size_t)n * OUT_DIM + lane] = acc[j] * dinv[n];
    }
}

// scatter edges into bucket regions; per-(block,bucket) ranges reserved with one
// global atomic, so writes to a bucket from a block are contiguous bursts that
// L2 merges into full lines.  Record: (src<<7) | (dst&127), 4 bytes.
__global__ __launch_bounds__(256) void k_bscatter(const int4* __restrict__ src4,
                                                  const int4* __restrict__ dst4, int E4,
                                                  int nbuck, int* __restrict__ gcursor,
                                                  int* __restrict__ sorted) {
    __shared__ int hcnt[MAXBUCK];
    __shared__ int hbase[MAXBUCK];
    for (int i = threadIdx.x; i < nbuck; i += 256) hcnt[i] = 0;
    __syncthreads();

    int base = blockIdx.x * 1024 + threadIdx.x;
    int4 sv[4], dv[4];
    bool ok[4];
    #pragma unroll
    for (int j = 0; j < 4; ++j) {
        int i4 = base + j * 256;
        ok[j] = (i4 < E4);
        if (ok[j]) {
            sv[j] = src4[i4];
            dv[j] = dst4[i4];
            atomicAdd(&hcnt[dv[j].x >> BSH], 1);
            atomicAdd(&hcnt[dv[j].y >> BSH], 1);
            atomicAdd(&hcnt[dv[j].z >> BSH], 1);
            atomicAdd(&hcnt[dv[j].w >> BSH], 1);
        }
    }
    __syncthreads();
    for (int i = threadIdx.x; i < nbuck; i += 256) {
        int c = hcnt[i];
        if (c) hbase[i] = atomicAdd(&gcursor[i], c);
        hcnt[i] = 0;
    }
    __syncthreads();
    #pragma unroll
    for (int j = 0; j < 4; ++j) {
        if (ok[j]) {
            int s, d, bk, r;
            s = sv[j].x; d = dv[j].x; bk = d >> BSH;
            r = atomicAdd(&hcnt[bk], 1);
            sorted[hbase[bk] + r] = (s << BSH) | (d & (BROWS - 1));
            s = sv[j].y; d = dv[j].y; bk = d >> BSH;
            r = atomicAdd(&hcnt[bk], 1);
            sorted[hbase[bk] + r] = (s << BSH) | (d & (BROWS - 1));
            s = sv[j].z; d = dv[j].z; bk = d >> BSH;
            r = atomicAdd(&hcnt[bk], 1);
            sorted[hbase[bk] + r] = (s << BSH) | (d & (BROWS - 1));
            s = sv[j].w; d = dv[j].w; bk = d >> BSH;
            r = atomicAdd(&hcnt[bk], 1);
            sorted[hbase[bk] + r] = (s << BSH) | (d & (BROWS - 1));
        }
    }
}

// one block per bucket: LDS accumulate + self loop + bias + BN + ReLU
__global__ __launch_bounds__(256) void k_agg2(const int* __restrict__ gbase,
                                              const int* __restrict__ sorted,
                                              const float* __restrict__ dinv,
                                              const float* __restrict__ m,
                                              const float* __restrict__ b,
                                              const float* __restrict__ gamma,
                                              const float* __restrict__ beta,
                                              const float* __restrict__ mean,
                                              const float* __restrict__ var,
                                              float* __restrict__ out, int N) {
    __shared__ float acc[BROWS * ASTR];   // 34.8 KB
    int tid = threadIdx.x;
    for (int i = tid; i < BROWS * ASTR; i += 256) acc[i] = 0.f;
    __syncthreads();

    int e0 = gbase[blockIdx.x];
    int e1 = gbase[blockIdx.x + 1];
    int sub = tid & 15;        // float4 chunk of the 64-dim row
    int slot = tid >> 4;       // 16 concurrent edge slots per block

    int e = e0 + slot;
    int rec = (e < e1) ? sorted[e] : -1;
    while (rec >= 0) {
        int en = e + 16;
        int rec2 = (en < e1) ? sorted[en] : -1;   // prefetch next record
        int s = rec >> BSH;
        int dl = rec & (BROWS - 1);
        float4 r = ((const float4*)m)[(size_t)s * 16 + sub];
        float* a = &acc[dl * ASTR + sub * 4];
        atomicAdd(a + 0, r.x);
        atomicAdd(a + 1, r.y);
        atomicAdd(a + 2, r.z);
        atomicAdd(a + 3, r.w);
        e = en;
        rec = rec2;
    }
    __syncthreads();

    int n0 = blockIdx.x << BSH;
    for (int i = tid; i < BROWS * 16; i += 256) {
        int rrow = i >> 4, s4 = i & 15;
        int n = n0 + rrow;
        if (n < N) {
            float4 mv = ((const float4*)m)[(size_t)n * 16 + s4];
            float dn = dinv[n];
            const float* a = &acc[rrow * ASTR + s4 * 4];
            float4 gg = ((const float4*)gamma)[s4];
            float4 vv = ((const float4*)var)[s4];
            float4 bb = ((const float4*)b)[s4];
            float4 mm = ((const float4*)mean)[s4];
            float4 be = ((const float4*)beta)[s4];
            float av[4] = {a[0] + mv.x, a[1] + mv.y, a[2] + mv.z, a[3] + mv.w};
            float gv[4] = {gg.x, gg.y, gg.z, gg.w};
            float vvv[4] = {vv.x, vv.y, vv.z, vv.w};
            float bv[4] = {bb.x, bb.y, bb.z, bb.w};
            float mvv[4] = {mm.x, mm.y, mm.z, mm.w};
            float ev[4] = {be.x, be.y, be.z, be.w};
            float4 o;
            float* op = (float*)&o;
            #pragma unroll
            for (int k = 0; k < 4; ++k) {
                float sc = gv[k] * rsqrtf(vvv[k] + BN_EPS);
                float v = (av[k] * dn + bv[k] - mvv[k]) * sc + ev[k];
                op[k] = v > 0.f ? v : 0.f;
            }
            ((float4*)out)[(size_t)n * 16 + s4] = o;
        }
    }
}

// ---------------- launcher ----------------

extern "C" void kernel_launch(void* const* d_in, const int* in_sizes, int n_in,
                              void* d_out, int out_size, void* d_ws, size_t ws_size,
                              hipStream_t stream) {
    const float* x     = (const float*)d_in[0];
    const int*   edges = (const int*)d_in[1];
    const float* W     = (const float*)d_in[2];
    const float* b     = (const float*)d_in[3];
    const float* gamma = (const float*)d_in[4];
    const float* beta  = (const float*)d_in[5];
    const float* rmean = (const float*)d_in[6];
    const float* rvar  = (const float*)d_in[7];
    float* out = (float*)d_out;

    int N = in_sizes[0] / IN_DIM;
    int E = in_sizes[1] / 2;
    const int* src = edges;
    const int* dst = edges + E;

    int nbuck = (N + BROWS - 1) >> BSH;     // 782
    int E4 = E >> 2;                        // 400000
    int nebk = (E4 + 1023) / 1024;          // 391

    // workspace layout
    char* ws = (char*)d_ws;
    size_t mB = (size_t)N * OUT_DIM * sizeof(float);            // 25.6 MB
    size_t eB = ((size_t)E * sizeof(int) + 255) & ~(size_t)255; // 6.4 MB
    float* m       = (float*)(ws);
    int*   sorted  = (int*)  (ws + mB);
    int*   deg     = (int*)  (ws + mB + eB);          // [N]      (zeroed)
    int*   gbcnt   = deg + N;                          // [nbuck]  (zeroed)
    int*   gbase   = gbcnt + nbuck;                    // [nbuck+1]
    int*   gcursor = gbase + nbuck + 1;                // [nbuck]
    float* dinv    = (float*)(gcursor + nbuck);        // [N]

    hipMemsetAsync(deg, 0, (size_t)(N + nbuck) * sizeof(int), stream);

    k_bhist<<<nebk, 256, 0, stream>>>((const int4*)dst, E4, nbuck, deg, gbcnt);
    k_bscan<<<1, 1024, 0, stream>>>(gbcnt, nbuck, E, gbase, gcursor);
    k_dinv<<<(N + 255) / 256, 256, 0, stream>>>(deg, dinv, N);
    k_gemm<<<(N + 15) / 16, 256, 0, stream>>>(x, W, dinv, m, N);
    k_bscatter<<<nebk, 256, 0, stream>>>((const int4*)src, (const int4*)dst, E4,
                                         nbuck, gcursor, sorted);
    k_agg2<<<nbuck, 256, 0, stream>>>(gbase, sorted, dinv, m, b, gamma, beta,
                                      rmean, rvar, out, N);
}

// Round 5
// 328.240 us; speedup vs baseline: 2.8286x; 2.8286x over previous
//
#include <hip/hip_runtime.h>
#include <hip/hip_bf16.h>

#define IN_DIM 128
#define OUT_DIM 64
#define BN_EPS 1e-5f
#define BSH 7                  // 128 nodes per bucket
#define BROWS 128
#define MAXBUCK 800            // LDS bound (>= nbuck = 782)

// ---------------- kernels ----------------

// bucket histogram (block-aggregated) + per-node degree, fused
__global__ __launch_bounds__(256) void k_bhist(const int4* __restrict__ dst4, int E4,
                                               int nbuck, int* __restrict__ deg,
                                               int* __restrict__ gbcnt) {
    __shared__ int hcnt[MAXBUCK];
    for (int i = threadIdx.x; i < nbuck; i += 256) hcnt[i] = 0;
    __syncthreads();
    int base = blockIdx.x * 1024 + threadIdx.x;
    #pragma unroll
    for (int j = 0; j < 4; ++j) {
        int i4 = base + j * 256;
        if (i4 < E4) {
            int4 v = dst4[i4];
            atomicAdd(&deg[v.x], 1); atomicAdd(&hcnt[v.x >> BSH], 1);
            atomicAdd(&deg[v.y], 1); atomicAdd(&hcnt[v.y >> BSH], 1);
            atomicAdd(&deg[v.z], 1); atomicAdd(&hcnt[v.z >> BSH], 1);
            atomicAdd(&deg[v.w], 1); atomicAdd(&hcnt[v.w >> BSH], 1);
        }
    }
    __syncthreads();
    for (int i = threadIdx.x; i < nbuck; i += 256)
        if (hcnt[i]) atomicAdd(&gbcnt[i], hcnt[i]);
}

// exclusive scan of bucket counts (nbuck <= 1024), one block
__global__ __launch_bounds__(1024) void k_bscan(const int* __restrict__ gbcnt, int nbuck,
                                                int E, int* __restrict__ gbase,
                                                int* __restrict__ gcursor) {
    __shared__ int sh[1024];
    int t = threadIdx.x;
    int v = (t < nbuck) ? gbcnt[t] : 0;
    sh[t] = v;
    __syncthreads();
    for (int d = 1; d < 1024; d <<= 1) {
        int tv = (t >= d) ? sh[t - d] : 0;
        __syncthreads();
        sh[t] += tv;
        __syncthreads();
    }
    if (t < nbuck) {
        int b = sh[t] - v;
        gbase[t] = b;
        gcursor[t] = b;
    }
    if (t == 1023) gbase[nbuck] = E;
}

__global__ __launch_bounds__(256) void k_dinv(const int* __restrict__ deg,
                                              float* __restrict__ dinv, int N) {
    int i = blockIdx.x * 256 + threadIdx.x;
    if (i < N) dinv[i] = rsqrtf((float)(deg[i] + 1));
}

// m = (x @ W) * dinv[n].  Block: 16 nodes, 4 waves; each wave computes 4 nodes.
__global__ __launch_bounds__(256) void k_gemm(const float* __restrict__ x,
                                              const float* __restrict__ W,
                                              const float* __restrict__ dinv,
                                              float* __restrict__ m, int N) {
    __shared__ float Wl[IN_DIM * OUT_DIM];  // 32 KB
    __shared__ float xl[16 * IN_DIM];       // 8 KB

    for (int i = threadIdx.x; i < (IN_DIM * OUT_DIM) / 4; i += 256)
        ((float4*)Wl)[i] = ((const float4*)W)[i];

    int node0 = blockIdx.x * 16;
    for (int i = threadIdx.x; i < 16 * IN_DIM / 4; i += 256) {
        int n = node0 + (i >> 5);
        if (n < N)
            ((float4*)xl)[i] = ((const float4*)x)[(size_t)node0 * (IN_DIM / 4) + i];
    }
    __syncthreads();

    int wave = threadIdx.x >> 6;
    int lane = threadIdx.x & 63;
    int nb = node0 + wave * 4;

    float acc[4] = {0.f, 0.f, 0.f, 0.f};
    for (int k0 = 0; k0 < IN_DIM; k0 += 4) {
        float4 xv0 = ((float4*)xl)[((wave * 4 + 0) * IN_DIM + k0) >> 2];
        float4 xv1 = ((float4*)xl)[((wave * 4 + 1) * IN_DIM + k0) >> 2];
        float4 xv2 = ((float4*)xl)[((wave * 4 + 2) * IN_DIM + k0) >> 2];
        float4 xv3 = ((float4*)xl)[((wave * 4 + 3) * IN_DIM + k0) >> 2];
        #pragma unroll
        for (int kk = 0; kk < 4; ++kk) {
            float w = Wl[(k0 + kk) * OUT_DIM + lane];
            acc[0] += ((float*)&xv0)[kk] * w;
            acc[1] += ((float*)&xv1)[kk] * w;
            acc[2] += ((float*)&xv2)[kk] * w;
            acc[3] += ((float*)&xv3)[kk] * w;
        }
    }
    #pragma unroll
    for (int j = 0; j < 4; ++j) {
        int n = nb + j;
        if (n < N) m[(size_t)n * OUT_DIM + lane] = acc[j] * dinv[n];
    }
}

// scatter edges into bucket regions; per-(block,bucket) ranges reserved with one
// global atomic, so writes to a bucket from a block are contiguous bursts that
// L2 merges into full lines.  Record: (src<<7) | (dst&127), 4 bytes.
__global__ __launch_bounds__(256) void k_bscatter(const int4* __restrict__ src4,
                                                  const int4* __restrict__ dst4, int E4,
                                                  int nbuck, int* __restrict__ gcursor,
                                                  int* __restrict__ recs) {
    __shared__ int hcnt[MAXBUCK];
    __shared__ int hbase[MAXBUCK];
    for (int i = threadIdx.x; i < nbuck; i += 256) hcnt[i] = 0;
    __syncthreads();

    int base = blockIdx.x * 1024 + threadIdx.x;
    int4 sv[4], dv[4];
    bool ok[4];
    #pragma unroll
    for (int j = 0; j < 4; ++j) {
        int i4 = base + j * 256;
        ok[j] = (i4 < E4);
        if (ok[j]) {
            sv[j] = src4[i4];
            dv[j] = dst4[i4];
            atomicAdd(&hcnt[dv[j].x >> BSH], 1);
            atomicAdd(&hcnt[dv[j].y >> BSH], 1);
            atomicAdd(&hcnt[dv[j].z >> BSH], 1);
            atomicAdd(&hcnt[dv[j].w >> BSH], 1);
        }
    }
    __syncthreads();
    for (int i = threadIdx.x; i < nbuck; i += 256) {
        int c = hcnt[i];
        if (c) hbase[i] = atomicAdd(&gcursor[i], c);
        hcnt[i] = 0;
    }
    __syncthreads();
    #pragma unroll
    for (int j = 0; j < 4; ++j) {
        if (ok[j]) {
            int s, d, bk, r;
            s = sv[j].x; d = dv[j].x; bk = d >> BSH;
            r = atomicAdd(&hcnt[bk], 1);
            recs[hbase[bk] + r] = (s << BSH) | (d & (BROWS - 1));
            s = sv[j].y; d = dv[j].y; bk = d >> BSH;
            r = atomicAdd(&hcnt[bk], 1);
            recs[hbase[bk] + r] = (s << BSH) | (d & (BROWS - 1));
            s = sv[j].z; d = dv[j].z; bk = d >> BSH;
            r = atomicAdd(&hcnt[bk], 1);
            recs[hbase[bk] + r] = (s << BSH) | (d & (BROWS - 1));
            s = sv[j].w; d = dv[j].w; bk = d >> BSH;
            r = atomicAdd(&hcnt[bk], 1);
            recs[hbase[bk] + r] = (s << BSH) | (d & (BROWS - 1));
        }
    }
}

// per-bucket counting sort -> full CSR order + offs[] from in-LDS prefix.
// One block per bucket; bucket region ~8KB so scattered writes L2-merge.
__global__ __launch_bounds__(256) void k_sort(const int* __restrict__ gbase,
                                              const int* __restrict__ recs,
                                              int* __restrict__ sorted,
                                              int* __restrict__ offs, int N) {
    __shared__ int hist[BROWS];
    __shared__ int cur[BROWS];
    __shared__ int sh[BROWS];
    int b = blockIdx.x;
    int e0 = gbase[b], e1 = gbase[b + 1];
    int tid = threadIdx.x;
    if (tid < BROWS) hist[tid] = 0;
    __syncthreads();
    for (int e = e0 + tid; e < e1; e += 256)
        atomicAdd(&hist[recs[e] & (BROWS - 1)], 1);
    __syncthreads();
    int v = (tid < BROWS) ? hist[tid] : 0;
    if (tid < BROWS) sh[tid] = v;
    __syncthreads();
    for (int d = 1; d < BROWS; d <<= 1) {
        int t = (tid < BROWS && tid >= d) ? sh[tid - d] : 0;
        __syncthreads();
        if (tid < BROWS) sh[tid] += t;
        __syncthreads();
    }
    if (tid < BROWS) {
        int pre = sh[tid] - v;      // exclusive prefix
        cur[tid] = pre;
        int n = (b << BSH) + tid;
        if (n < N) offs[n] = e0 + pre;
    }
    __syncthreads();
    for (int e = e0 + tid; e < e1; e += 256) {
        int r = recs[e];
        int p = atomicAdd(&cur[r & (BROWS - 1)], 1);
        sorted[e0 + p] = r >> BSH;    // bare src index
    }
}

// fused CSR gather-aggregate + self loop + BN + ReLU.  One wave per node.
// Lane layout: g = lane>>4 (edge slot 0..3), sub = lane&15 (float4 chunk).
// Each instruction gathers 4 full rows (1KB/wave); unroll x2 -> 8 in flight.
__global__ __launch_bounds__(256) void k_agg(const int* __restrict__ offs,
                                             const int* __restrict__ sorted,
                                             const float* __restrict__ dinv,
                                             const float* __restrict__ m,
                                             const float* __restrict__ b,
                                             const float* __restrict__ gamma,
                                             const float* __restrict__ beta,
                                             const float* __restrict__ mean,
                                             const float* __restrict__ var,
                                             float* __restrict__ out, int N, int E) {
    int wid = (blockIdx.x * 256 + threadIdx.x) >> 6;
    int lane = threadIdx.x & 63;
    if (wid >= N) return;
    int n = wid;
    int s0 = offs[n];
    int s1 = (n == N - 1) ? E : offs[n + 1];
    int g = lane >> 4;
    int sub = lane & 15;

    float4 acc0 = {0.f, 0.f, 0.f, 0.f};
    float4 acc1 = {0.f, 0.f, 0.f, 0.f};
    int e = s0;
    for (; e + 8 <= s1; e += 8) {
        int sA = sorted[e + g];
        int sB = sorted[e + 4 + g];
        float4 ra = ((const float4*)m)[(size_t)sA * 16 + sub];
        float4 rb = ((const float4*)m)[(size_t)sB * 16 + sub];
        acc0.x += ra.x; acc0.y += ra.y; acc0.z += ra.z; acc0.w += ra.w;
        acc1.x += rb.x; acc1.y += rb.y; acc1.z += rb.z; acc1.w += rb.w;
    }
    for (; e < s1; e += 4) {
        int idx = e + g;
        if (idx < s1) {
            int sA = sorted[idx];
            float4 ra = ((const float4*)m)[(size_t)sA * 16 + sub];
            acc0.x += ra.x; acc0.y += ra.y; acc0.z += ra.z; acc0.w += ra.w;
        }
    }
    acc0.x += acc1.x; acc0.y += acc1.y; acc0.z += acc1.z; acc0.w += acc1.w;

    #pragma unroll
    for (int mask = 16; mask <= 32; mask <<= 1) {
        acc0.x += __shfl_xor(acc0.x, mask, 64);
        acc0.y += __shfl_xor(acc0.y, mask, 64);
        acc0.z += __shfl_xor(acc0.z, mask, 64);
        acc0.w += __shfl_xor(acc0.w, mask, 64);
    }

    if (lane < 16) {
        float4 self = ((const float4*)m)[(size_t)n * 16 + sub];
        float dn = dinv[n];
        float4 gg = ((const float4*)gamma)[sub];
        float4 vv = ((const float4*)var)[sub];
        float4 bb = ((const float4*)b)[sub];
        float4 mm = ((const float4*)mean)[sub];
        float4 be = ((const float4*)beta)[sub];
        float4 o;
        float* op = (float*)&o;
        float av[4] = {acc0.x + self.x, acc0.y + self.y,
                       acc0.z + self.z, acc0.w + self.w};
        float gv[4] = {gg.x, gg.y, gg.z, gg.w};
        float vvv[4] = {vv.x, vv.y, vv.z, vv.w};
        float bv[4] = {bb.x, bb.y, bb.z, bb.w};
        float mv[4] = {mm.x, mm.y, mm.z, mm.w};
        float ev[4] = {be.x, be.y, be.z, be.w};
        #pragma unroll
        for (int j = 0; j < 4; ++j) {
            float sc = gv[j] * rsqrtf(vvv[j] + BN_EPS);
            float vval = (av[j] * dn + bv[j] - mv[j]) * sc + ev[j];
            op[j] = vval > 0.f ? vval : 0.f;
        }
        ((float4*)out)[(size_t)n * 16 + sub] = o;
    }
}

// ---------------- launcher ----------------

extern "C" void kernel_launch(void* const* d_in, const int* in_sizes, int n_in,
                              void* d_out, int out_size, void* d_ws, size_t ws_size,
                              hipStream_t stream) {
    const float* x     = (const float*)d_in[0];
    const int*   edges = (const int*)d_in[1];
    const float* W     = (const float*)d_in[2];
    const float* b     = (const float*)d_in[3];
    const float* gamma = (const float*)d_in[4];
    const float* beta  = (const float*)d_in[5];
    const float* rmean = (const float*)d_in[6];
    const float* rvar  = (const float*)d_in[7];
    float* out = (float*)d_out;

    int N = in_sizes[0] / IN_DIM;
    int E = in_sizes[1] / 2;
    const int* src = edges;
    const int* dst = edges + E;

    int nbuck = (N + BROWS - 1) >> BSH;     // 782
    int E4 = E >> 2;                        // 400000
    int nebk = (E4 + 1023) / 1024;          // 391

    // workspace layout
    char* ws = (char*)d_ws;
    size_t mB = (size_t)N * OUT_DIM * sizeof(float);            // 25.6 MB
    size_t eB = ((size_t)E * sizeof(int) + 255) & ~(size_t)255; // 6.4 MB
    float* m       = (float*)(ws);
    int*   recs    = (int*)  (ws + mB);                // [E]
    int*   sorted  = (int*)  (ws + mB + eB);           // [E]
    int*   deg     = (int*)  (ws + mB + 2 * eB);       // [N]      (zeroed)
    int*   gbcnt   = deg + N;                          // [nbuck]  (zeroed)
    int*   gbase   = gbcnt + nbuck;                    // [nbuck+1]
    int*   gcursor = gbase + nbuck + 1;                // [nbuck]
    float* dinv    = (float*)(gcursor + nbuck);        // [N]
    int*   offs    = (int*)(dinv + N);                 // [N]

    hipMemsetAsync(deg, 0, (size_t)(N + nbuck) * sizeof(int), stream);

    k_bhist<<<nebk, 256, 0, stream>>>((const int4*)dst, E4, nbuck, deg, gbcnt);
    k_bscan<<<1, 1024, 0, stream>>>(gbcnt, nbuck, E, gbase, gcursor);
    k_dinv<<<(N + 255) / 256, 256, 0, stream>>>(deg, dinv, N);
    k_gemm<<<(N + 15) / 16, 256, 0, stream>>>(x, W, dinv, m, N);
    k_bscatter<<<nebk, 256, 0, stream>>>((const int4*)src, (const int4*)dst, E4,
                                         nbuck, gcursor, recs);
    k_sort<<<nbuck, 256, 0, stream>>>(gbase, recs, sorted, offs, N);
    k_agg<<<(N + 3) / 4, 256, 0, stream>>>(offs, sorted, dinv, m, b, gamma, beta,
                                           rmean, rvar, out, N, E);
}

// Round 6
// 265.495 us; speedup vs baseline: 3.4971x; 1.2363x over previous
//
#include <hip/hip_runtime.h>
#include <hip/hip_bf16.h>

#define IN_DIM 128
#define OUT_DIM 64
#define BN_EPS 1e-5f
#define BSH 7                  // 128 nodes per bucket
#define BROWS 128
#define MAXBUCK 800            // LDS bound (>= nbuck = 782)

// ---------------- kernels ----------------

// bucket histogram only (block-aggregated flush); per-node degree comes from k_sort
__global__ __launch_bounds__(256) void k_bhist(const int4* __restrict__ dst4, int E4,
                                               int nbuck, int* __restrict__ gbcnt) {
    __shared__ int hcnt[MAXBUCK];
    for (int i = threadIdx.x; i < nbuck; i += 256) hcnt[i] = 0;
    __syncthreads();
    int base = blockIdx.x * 1024 + threadIdx.x;
    #pragma unroll
    for (int j = 0; j < 4; ++j) {
        int i4 = base + j * 256;
        if (i4 < E4) {
            int4 v = dst4[i4];
            atomicAdd(&hcnt[v.x >> BSH], 1);
            atomicAdd(&hcnt[v.y >> BSH], 1);
            atomicAdd(&hcnt[v.z >> BSH], 1);
            atomicAdd(&hcnt[v.w >> BSH], 1);
        }
    }
    __syncthreads();
    for (int i = threadIdx.x; i < nbuck; i += 256)
        if (hcnt[i]) atomicAdd(&gbcnt[i], hcnt[i]);
}

// exclusive scan of bucket counts (nbuck <= 1024), one block
__global__ __launch_bounds__(1024) void k_bscan(const int* __restrict__ gbcnt, int nbuck,
                                                int E, int* __restrict__ gbase,
                                                int* __restrict__ gcursor) {
    __shared__ int sh[1024];
    int t = threadIdx.x;
    int v = (t < nbuck) ? gbcnt[t] : 0;
    sh[t] = v;
    __syncthreads();
    for (int d = 1; d < 1024; d <<= 1) {
        int tv = (t >= d) ? sh[t - d] : 0;
        __syncthreads();
        sh[t] += tv;
        __syncthreads();
    }
    if (t < nbuck) {
        int b = sh[t] - v;
        gbase[t] = b;
        gcursor[t] = b;
    }
    if (t == 1023) gbase[nbuck] = E;
}

// scatter edges into bucket regions.  Rank assigned during the (single) LDS
// histogram pass; per-(block,bucket) ranges reserved with one global atomic so
// writes to a bucket are contiguous bursts that L2 merges.
// Record: (src<<7) | (dst&127), 4 bytes.
__global__ __launch_bounds__(256) void k_bscatter(const int4* __restrict__ src4,
                                                  const int4* __restrict__ dst4, int E4,
                                                  int nbuck, int* __restrict__ gcursor,
                                                  int* __restrict__ recs) {
    __shared__ int hcnt[MAXBUCK];
    __shared__ int hbase[MAXBUCK];
    for (int i = threadIdx.x; i < nbuck; i += 256) hcnt[i] = 0;
    __syncthreads();

    int base = blockIdx.x * 1024 + threadIdx.x;
    int rec[16], bk[16], rk[16];
    int cnt = 0;
    #pragma unroll
    for (int j = 0; j < 4; ++j) {
        int i4 = base + j * 256;
        if (i4 < E4) {
            int4 s = src4[i4];
            int4 d = dst4[i4];
            bk[cnt] = d.x >> BSH; rec[cnt] = (s.x << BSH) | (d.x & (BROWS - 1));
            rk[cnt] = atomicAdd(&hcnt[bk[cnt]], 1); ++cnt;
            bk[cnt] = d.y >> BSH; rec[cnt] = (s.y << BSH) | (d.y & (BROWS - 1));
            rk[cnt] = atomicAdd(&hcnt[bk[cnt]], 1); ++cnt;
            bk[cnt] = d.z >> BSH; rec[cnt] = (s.z << BSH) | (d.z & (BROWS - 1));
            rk[cnt] = atomicAdd(&hcnt[bk[cnt]], 1); ++cnt;
            bk[cnt] = d.w >> BSH; rec[cnt] = (s.w << BSH) | (d.w & (BROWS - 1));
            rk[cnt] = atomicAdd(&hcnt[bk[cnt]], 1); ++cnt;
        }
    }
    __syncthreads();
    for (int i = threadIdx.x; i < nbuck; i += 256) {
        int c = hcnt[i];
        if (c) hbase[i] = atomicAdd(&gcursor[i], c);
    }
    __syncthreads();
    for (int j = 0; j < cnt; ++j)
        recs[hbase[bk[j]] + rk[j]] = rec[j];
}

// per-bucket counting sort -> CSR order + offs[] + dinv[] (degree from hist).
__global__ __launch_bounds__(256) void k_sort(const int* __restrict__ gbase,
                                              const int* __restrict__ recs,
                                              int* __restrict__ sorted,
                                              int* __restrict__ offs,
                                              float* __restrict__ dinv, int N) {
    __shared__ int hist[BROWS];
    __shared__ int cur[BROWS];
    __shared__ int sh[BROWS];
    int b = blockIdx.x;
    int e0 = gbase[b], e1 = gbase[b + 1];
    int tid = threadIdx.x;
    if (tid < BROWS) hist[tid] = 0;
    __syncthreads();
    for (int e = e0 + tid; e < e1; e += 256)
        atomicAdd(&hist[recs[e] & (BROWS - 1)], 1);
    __syncthreads();
    int v = (tid < BROWS) ? hist[tid] : 0;
    if (tid < BROWS) sh[tid] = v;
    __syncthreads();
    for (int d = 1; d < BROWS; d <<= 1) {
        int t = (tid < BROWS && tid >= d) ? sh[tid - d] : 0;
        __syncthreads();
        if (tid < BROWS) sh[tid] += t;
        __syncthreads();
    }
    if (tid < BROWS) {
        int pre = sh[tid] - v;      // exclusive prefix
        cur[tid] = pre;
        int n = (b << BSH) + tid;
        if (n < N) {
            offs[n] = e0 + pre;
            dinv[n] = rsqrtf((float)(v + 1));   // degree + self loop
        }
    }
    __syncthreads();
    for (int e = e0 + tid; e < e1; e += 256) {
        int r = recs[e];
        int p = atomicAdd(&cur[r & (BROWS - 1)], 1);
        sorted[e0 + p] = r >> BSH;    // bare src index
    }
}

// m = (x @ W) * dinv[n].  Block: 16 nodes, 4 waves; each wave computes 4 nodes.
__global__ __launch_bounds__(256) void k_gemm(const float* __restrict__ x,
                                              const float* __restrict__ W,
                                              const float* __restrict__ dinv,
                                              float* __restrict__ m, int N) {
    __shared__ float Wl[IN_DIM * OUT_DIM];  // 32 KB
    __shared__ float xl[16 * IN_DIM];       // 8 KB

    for (int i = threadIdx.x; i < (IN_DIM * OUT_DIM) / 4; i += 256)
        ((float4*)Wl)[i] = ((const float4*)W)[i];

    int node0 = blockIdx.x * 16;
    for (int i = threadIdx.x; i < 16 * IN_DIM / 4; i += 256) {
        int n = node0 + (i >> 5);
        if (n < N)
            ((float4*)xl)[i] = ((const float4*)x)[(size_t)node0 * (IN_DIM / 4) + i];
    }
    __syncthreads();

    int wave = threadIdx.x >> 6;
    int lane = threadIdx.x & 63;
    int nb = node0 + wave * 4;

    float acc[4] = {0.f, 0.f, 0.f, 0.f};
    for (int k0 = 0; k0 < IN_DIM; k0 += 4) {
        float4 xv0 = ((float4*)xl)[((wave * 4 + 0) * IN_DIM + k0) >> 2];
        float4 xv1 = ((float4*)xl)[((wave * 4 + 1) * IN_DIM + k0) >> 2];
        float4 xv2 = ((float4*)xl)[((wave * 4 + 2) * IN_DIM + k0) >> 2];
        float4 xv3 = ((float4*)xl)[((wave * 4 + 3) * IN_DIM + k0) >> 2];
        #pragma unroll
        for (int kk = 0; kk < 4; ++kk) {
            float w = Wl[(k0 + kk) * OUT_DIM + lane];
            acc[0] += ((float*)&xv0)[kk] * w;
            acc[1] += ((float*)&xv1)[kk] * w;
            acc[2] += ((float*)&xv2)[kk] * w;
            acc[3] += ((float*)&xv3)[kk] * w;
        }
    }
    #pragma unroll
    for (int j = 0; j < 4; ++j) {
        int n = nb + j;
        if (n < N) m[(size_t)n * OUT_DIM + lane] = acc[j] * dinv[n];
    }
}

// fused CSR gather-aggregate + self loop + BN + ReLU.  One wave per node.
// Lane layout: g = lane>>4 (edge slot 0..3), sub = lane&15 (float4 chunk).
__global__ __launch_bounds__(256) void k_agg(const int* __restrict__ offs,
                                             const int* __restrict__ sorted,
                                             const float* __restrict__ dinv,
                                             const float* __restrict__ m,
                                             const float* __restrict__ b,
                                             const float* __restrict__ gamma,
                                             const float* __restrict__ beta,
                                             const float* __restrict__ mean,
                                             const float* __restrict__ var,
                                             float* __restrict__ out, int N, int E) {
    int wid = (blockIdx.x * 256 + threadIdx.x) >> 6;
    int lane = threadIdx.x & 63;
    if (wid >= N) return;
    int n = wid;
    int s0 = offs[n];
    int s1 = (n == N - 1) ? E : offs[n + 1];
    int g = lane >> 4;
    int sub = lane & 15;

    float4 acc0 = {0.f, 0.f, 0.f, 0.f};
    float4 acc1 = {0.f, 0.f, 0.f, 0.f};
    int e = s0;
    for (; e + 8 <= s1; e += 8) {
        int sA = sorted[e + g];
        int sB = sorted[e + 4 + g];
        float4 ra = ((const float4*)m)[(size_t)sA * 16 + sub];
        float4 rb = ((const float4*)m)[(size_t)sB * 16 + sub];
        acc0.x += ra.x; acc0.y += ra.y; acc0.z += ra.z; acc0.w += ra.w;
        acc1.x += rb.x; acc1.y += rb.y; acc1.z += rb.z; acc1.w += rb.w;
    }
    for (; e < s1; e += 4) {
        int idx = e + g;
        if (idx < s1) {
            int sA = sorted[idx];
            float4 ra = ((const float4*)m)[(size_t)sA * 16 + sub];
            acc0.x += ra.x; acc0.y += ra.y; acc0.z += ra.z; acc0.w += ra.w;
        }
    }
    acc0.x += acc1.x; acc0.y += acc1.y; acc0.z += acc1.z; acc0.w += acc1.w;

    #pragma unroll
    for (int mask = 16; mask <= 32; mask <<= 1) {
        acc0.x += __shfl_xor(acc0.x, mask, 64);
        acc0.y += __shfl_xor(acc0.y, mask, 64);
        acc0.z += __shfl_xor(acc0.z, mask, 64);
        acc0.w += __shfl_xor(acc0.w, mask, 64);
    }

    if (lane < 16) {
        float4 self = ((const float4*)m)[(size_t)n * 16 + sub];
        float dn = dinv[n];
        float4 gg = ((const float4*)gamma)[sub];
        float4 vv = ((const float4*)var)[sub];
        float4 bb = ((const float4*)b)[sub];
        float4 mm = ((const float4*)mean)[sub];
        float4 be = ((const float4*)beta)[sub];
        float4 o;
        float* op = (float*)&o;
        float av[4] = {acc0.x + self.x, acc0.y + self.y,
                       acc0.z + self.z, acc0.w + self.w};
        float gv[4] = {gg.x, gg.y, gg.z, gg.w};
        float vvv[4] = {vv.x, vv.y, vv.z, vv.w};
        float bv[4] = {bb.x, bb.y, bb.z, bb.w};
        float mv[4] = {mm.x, mm.y, mm.z, mm.w};
        float ev[4] = {be.x, be.y, be.z, be.w};
        #pragma unroll
        for (int j = 0; j < 4; ++j) {
            float sc = gv[j] * rsqrtf(vvv[j] + BN_EPS);
            float vval = (av[j] * dn + bv[j] - mv[j]) * sc + ev[j];
            op[j] = vval > 0.f ? vval : 0.f;
        }
        ((float4*)out)[(size_t)n * 16 + sub] = o;
    }
}

// ---------------- launcher ----------------

extern "C" void kernel_launch(void* const* d_in, const int* in_sizes, int n_in,
                              void* d_out, int out_size, void* d_ws, size_t ws_size,
                              hipStream_t stream) {
    const float* x     = (const float*)d_in[0];
    const int*   edges = (const int*)d_in[1];
    const float* W     = (const float*)d_in[2];
    const float* b     = (const float*)d_in[3];
    const float* gamma = (const float*)d_in[4];
    const float* beta  = (const float*)d_in[5];
    const float* rmean = (const float*)d_in[6];
    const float* rvar  = (const float*)d_in[7];
    float* out = (float*)d_out;

    int N = in_sizes[0] / IN_DIM;
    int E = in_sizes[1] / 2;
    const int* src = edges;
    const int* dst = edges + E;

    int nbuck = (N + BROWS - 1) >> BSH;     // 782
    int E4 = E >> 2;                        // 400000
    int nebk = (E4 + 1023) / 1024;          // 391

    // workspace layout
    char* ws = (char*)d_ws;
    size_t mB = (size_t)N * OUT_DIM * sizeof(float);            // 25.6 MB
    size_t eB = ((size_t)E * sizeof(int) + 255) & ~(size_t)255; // 6.4 MB
    float* m       = (float*)(ws);
    int*   recs    = (int*)  (ws + mB);                // [E]
    int*   sorted  = (int*)  (ws + mB + eB);           // [E]
    int*   gbcnt   = (int*)  (ws + mB + 2 * eB);       // [nbuck]  (zeroed)
    int*   gbase   = gbcnt + nbuck;                    // [nbuck+1]
    int*   gcursor = gbase + nbuck + 1;                // [nbuck]
    float* dinv    = (float*)(gcursor + nbuck);        // [N]
    int*   offs    = (int*)(dinv + N);                 // [N]

    hipMemsetAsync(gbcnt, 0, (size_t)nbuck * sizeof(int), stream);

    k_bhist<<<nebk, 256, 0, stream>>>((const int4*)dst, E4, nbuck, gbcnt);
    k_bscan<<<1, 1024, 0, stream>>>(gbcnt, nbuck, E, gbase, gcursor);
    k_bscatter<<<nebk, 256, 0, stream>>>((const int4*)src, (const int4*)dst, E4,
                                         nbuck, gcursor, recs);
    k_sort<<<nbuck, 256, 0, stream>>>(gbase, recs, sorted, offs, dinv, N);
    k_gemm<<<(N + 15) / 16, 256, 0, stream>>>(x, W, dinv, m, N);
    k_agg<<<(N + 3) / 4, 256, 0, stream>>>(offs, sorted, dinv, m, b, gamma, beta,
                                           rmean, rvar, out, N, E);
}